// Round 12
// baseline (130.603 us; speedup 1.0000x reference)
//
#include <hip/hip_runtime.h>
#include <math.h>

#define LOG2E 1.44269504088896340736f

typedef __attribute__((ext_vector_type(8))) short bfrag;   // 8 x bf16
typedef __attribute__((ext_vector_type(4))) float f4;
typedef unsigned __attribute__((ext_vector_type(2))) u2;

// ---------- helpers ----------
// D = (hi16(a)) | (hi16(b)<<16)  -- single v_perm_b32 where available
__device__ __forceinline__ unsigned pk_trunc(float a, float b) {
#if __has_builtin(__builtin_amdgcn_perm)
    return __builtin_amdgcn_perm(__float_as_uint(b), __float_as_uint(a), 0x07060302u);
#else
    return (__float_as_uint(a) >> 16) | (__float_as_uint(b) & 0xFFFF0000u);
#endif
}
__device__ __forceinline__ unsigned pk_rne(float a, float b) {
    unsigned ua = __float_as_uint(a); ua += 0x7FFFu + ((ua >> 16) & 1u);
    unsigned ub = __float_as_uint(b); ub += 0x7FFFu + ((ub >> 16) & 1u);
    return (ua >> 16) | (ub & 0xFFFF0000u);
}
__device__ __forceinline__ float trunchi(float x) {
    return __uint_as_float(__float_as_uint(x) & 0xFFFF0000u);
}
__device__ __forceinline__ float fexp2(float x) {
#if __has_builtin(__builtin_amdgcn_exp2f)
    return __builtin_amdgcn_exp2f(x);
#else
    return exp2f(x);
#endif
}
// async global->LDS, 16B/lane; lds base wave-uniform, HW lands lane i at base+i*16
__device__ __forceinline__ void stage16(void* lds_base, const void* g) {
#if __has_builtin(__builtin_amdgcn_global_load_lds)
    __builtin_amdgcn_global_load_lds(
        (const __attribute__((address_space(1))) unsigned int*)g,
        (__attribute__((address_space(3))) unsigned int*)lds_base, 16, 0, 0);
#else
    int lane = threadIdx.x & 63;
    *(float4*)((char*)lds_base + lane * 16) = *(const float4*)g;
#endif
}
__device__ __forceinline__ f4 mfma_bf16(bfrag a, bfrag b, f4 c) {
    return __builtin_amdgcn_mfma_f32_16x16x32_bf16(a, b, c, 0, 0, 0);
}
// pack two f4 (8 consecutive values) into hi/lo bf16 fragment halves
__device__ __forceinline__ void conv8v(f4 a, f4 b, bfrag& hi, bfrag& lo) {
    union { unsigned u[4]; bfrag v; } H, L;
    H.u[0] = pk_trunc(a.x, a.y); H.u[1] = pk_trunc(a.z, a.w);
    H.u[2] = pk_trunc(b.x, b.y); H.u[3] = pk_trunc(b.z, b.w);
    L.u[0] = pk_trunc(a.x - trunchi(a.x), a.y - trunchi(a.y));
    L.u[1] = pk_trunc(a.z - trunchi(a.z), a.w - trunchi(a.w));
    L.u[2] = pk_trunc(b.x - trunchi(b.x), b.y - trunchi(b.y));
    L.u[3] = pk_trunc(b.z - trunchi(b.z), b.w - trunchi(b.w));
    hi = H.v; lo = L.v;
}
__device__ __forceinline__ void conv8(const float* __restrict__ g, bfrag& hi, bfrag& lo) {
    conv8v(*(const f4*)g, *(const f4*)(g + 4), hi, lo);
}
// scaled variant (scale applied in fp32 BEFORE split)
__device__ __forceinline__ void conv8s(const float* __restrict__ g, float s,
                                       bfrag& hi, bfrag& lo) {
    f4 a = *(const f4*)g, b = *(const f4*)(g + 4);
    a.x *= s; a.y *= s; a.z *= s; a.w *= s;
    b.x *= s; b.y *= s; b.z *= s; b.w *= s;
    conv8v(a, b, hi, lo);
}
// DIRECT packing (no cross-lane): frag k-positions j0..3 = ea regs, j4..7 = eb
// regs. The implied k-permutation is baked consistently into BOTH MFMA
// operands everywhere (q'&k' for S; vt for PV; Wo-pi for out) so it cancels.
__device__ __forceinline__ void store_q2(f4 ea, f4 eb, char* base, int lodelta, int lane) {
    union { unsigned u[4]; bfrag v; } H, L;
    H.u[0] = pk_trunc(ea[0], ea[1]); H.u[1] = pk_trunc(ea[2], ea[3]);
    H.u[2] = pk_trunc(eb[0], eb[1]); H.u[3] = pk_trunc(eb[2], eb[3]);
    L.u[0] = pk_trunc(ea[0] - trunchi(ea[0]), ea[1] - trunchi(ea[1]));
    L.u[1] = pk_trunc(ea[2] - trunchi(ea[2]), ea[3] - trunchi(ea[3]));
    L.u[2] = pk_trunc(eb[0] - trunchi(eb[0]), eb[1] - trunchi(eb[1]));
    L.u[3] = pk_trunc(eb[2] - trunchi(eb[2]), eb[3] - trunchi(eb[3]));
    *(bfrag*)(base + lane * 16) = H.v;
    *(bfrag*)(base + lodelta + lane * 16) = L.v;
}
__device__ __forceinline__ void store_rne2(f4 ea, f4 eb, char* base, int lane) {
    union { unsigned u[4]; bfrag v; } P;
    P.u[0] = pk_rne(ea[0], ea[1]); P.u[1] = pk_rne(ea[2], ea[3]);
    P.u[2] = pk_rne(eb[0], eb[1]); P.u[3] = pk_rne(eb[2], eb[3]);
    *(bfrag*)(base + lane * 16) = P.v;
}

// ---------- workspace byte offsets ----------
// qb:   [bh][128 panels][hi 1KB | lo 1KB]                 = 8,388,608
// kv:   [bh][32 chunks][k 4KB | vt 2KB]  (64 keys/chunk)  = 6,291,456
// xp:   [2 ks][512 panels][4 kg][2 half][64 lanes][16B]   = 8,388,608  (fp32 o partials)
// lbuf: [2 ks][32 bh][2048] fp32                          = 524,288
#define WS_QB 0u
#define WS_KV 8388608u
#define WS_XP 14680064u
#define WS_L  23068672u

// ---------- MFMA projections (input-shared, self-converted W) ----------
// Grid (256, 2): x -> (batch, 32 seq rows), y = head-group (4 heads).
__global__ __launch_bounds__(256) void k_proj(
    const float* __restrict__ query, const float* __restrict__ key,
    const float* __restrict__ value, const float* __restrict__ pos,
    const float* __restrict__ W0, const float* __restrict__ W1,
    const float* __restrict__ W2,
    const float* __restrict__ b0, const float* __restrict__ b1,
    const float* __restrict__ b2,
    char* __restrict__ qb, char* __restrict__ kv)
{
    __shared__ __align__(16) char xlds[65536];   // [arr 4][panel 2][kg 4][hi 1K|lo 1K]
    const int tid = threadIdx.x;
    const int bid = blockIdx.x;
    const int b = bid >> 6, s32 = bid & 63;
    const size_t rowbase = (size_t)(b * 2048 + s32 * 32);

    // ---- phase 0: stage + convert ----
#pragma unroll
    for (int i = 0; i < 8; ++i) {
        int cid = tid + i * 256;                 // 0..2047
        int arr = cid >> 9, rem = cid & 511;
        int c32 = rem >> 4, u = rem & 15;        // row-in-block, dim-chunk
        const float* sp = (arr == 0) ? query : (arr == 1) ? key
                        : (arr == 2) ? value : pos;     // wave-uniform per i
        bfrag hi, lo;
        conv8(sp + (rowbase + c32) * 128 + u * 8, hi, lo);
        int base = arr * 16384 + (c32 >> 4) * 8192 + (u >> 2) * 2048
                 + ((u & 3) * 16 + (c32 & 15)) * 16;
        *(bfrag*)(xlds + base) = hi;
        *(bfrag*)(xlds + base + 1024) = lo;
    }
    __syncthreads();

    // ---- phase 1: one head per wave ----
    const int w = tid >> 6, lane = tid & 63;
    const int n = lane & 15, qd = lane >> 4;
    const int h = blockIdx.y * 4 + w;
    const int bh = b * 8 + h;
    const size_t wrow = (size_t)(h * 16 + n) * 128 + qd * 8;   // W row/cols per lane

    // -- Q: q' = [0.25L*(query W0^T + b0) || L*(pos W0^T + b0)] --
    {
        bfrag wqh[4], wql[4], wph[4], wpl[4];
#pragma unroll
        for (int kg = 0; kg < 4; ++kg) {
            conv8s(W0 + wrow + kg * 32, 0.25f * LOG2E, wqh[kg], wql[kg]);
            conv8s(W0 + wrow + kg * 32, LOG2E, wph[kg], wpl[kg]);
        }
        float bq[4], bp[4];
#pragma unroll
        for (int r = 0; r < 4; ++r) {
            float bv = b0[h * 16 + qd * 4 + r];
            bq[r] = 0.25f * LOG2E * bv; bp[r] = LOG2E * bv;
        }
#pragma unroll
        for (int pp = 0; pp < 2; ++pp) {
            f4 cq = {bq[0], bq[1], bq[2], bq[3]};
            f4 cp = {bp[0], bp[1], bp[2], bp[3]};
#pragma unroll
            for (int kg = 0; kg < 4; ++kg) {
                const char* xq = xlds + 0 * 16384 + pp * 8192 + kg * 2048 + lane * 16;
                const char* xp_ = xlds + 3 * 16384 + pp * 8192 + kg * 2048 + lane * 16;
                bfrag xh = *(const bfrag*)xq, xl = *(const bfrag*)(xq + 1024);
                bfrag ph = *(const bfrag*)xp_, pl = *(const bfrag*)(xp_ + 1024);
                cq = mfma_bf16(wqh[kg], xh, cq);
                cq = mfma_bf16(wqh[kg], xl, cq);
                cq = mfma_bf16(wql[kg], xh, cq);
                cp = mfma_bf16(wph[kg], ph, cp);
                cp = mfma_bf16(wph[kg], pl, cp);
                cp = mfma_bf16(wpl[kg], ph, cp);
            }
            int pg = s32 * 2 + pp;
            store_q2(cq, cp, qb + (size_t)bh * 262144 + (size_t)pg * 2048, 1024, lane);
        }
    }
    // -- K: k' = [(key W1^T + b1) || (pos W1^T + b1)], RNE bf16 --
    {
        bfrag w1h[4], w1l[4];
#pragma unroll
        for (int kg = 0; kg < 4; ++kg)
            conv8(W1 + wrow + kg * 32, w1h[kg], w1l[kg]);
        float bk[4];
#pragma unroll
        for (int r = 0; r < 4; ++r) bk[r] = b1[h * 16 + qd * 4 + r];
#pragma unroll
        for (int pp = 0; pp < 2; ++pp) {
            f4 ck = {bk[0], bk[1], bk[2], bk[3]};
            f4 cpk = {bk[0], bk[1], bk[2], bk[3]};
#pragma unroll
            for (int kg = 0; kg < 4; ++kg) {
                const char* xk = xlds + 1 * 16384 + pp * 8192 + kg * 2048 + lane * 16;
                const char* xp_ = xlds + 3 * 16384 + pp * 8192 + kg * 2048 + lane * 16;
                bfrag xh = *(const bfrag*)xk, xl = *(const bfrag*)(xk + 1024);
                bfrag ph = *(const bfrag*)xp_, pl = *(const bfrag*)(xp_ + 1024);
                ck = mfma_bf16(w1h[kg], xh, ck);
                ck = mfma_bf16(w1h[kg], xl, ck);
                ck = mfma_bf16(w1l[kg], xh, ck);
                cpk = mfma_bf16(w1h[kg], ph, cpk);
                cpk = mfma_bf16(w1h[kg], pl, cpk);
                cpk = mfma_bf16(w1l[kg], ph, cpk);
            }
            int pg = s32 * 2 + pp;   // 16-key panel id; chunk = pg>>2 (64 keys)
            store_rne2(ck, cpk,
                       kv + (size_t)bh * 196608 + (size_t)(pg >> 2) * 6144
                       + (pg & 3) * 1024, lane);
        }
    }
    // -- V: vt = value W2^T + b2 (normal orientation, RNE bf16) --
    {
        bfrag w2h[4], w2l[4];
#pragma unroll
        for (int kg = 0; kg < 4; ++kg)
            conv8(W2 + wrow + kg * 32, w2h[kg], w2l[kg]);
        float bv = b2[h * 16 + n];
        f4 ca = {bv, bv, bv, bv};
        f4 cb = {bv, bv, bv, bv};
#pragma unroll
        for (int pp = 0; pp < 2; ++pp) {
#pragma unroll
            for (int kg = 0; kg < 4; ++kg) {
                const char* xv = xlds + 2 * 16384 + pp * 8192 + kg * 2048 + lane * 16;
                bfrag ah = *(const bfrag*)xv, al = *(const bfrag*)(xv + 1024);
                if (pp == 0) {
                    ca = mfma_bf16(ah, w2h[kg], ca);
                    ca = mfma_bf16(al, w2h[kg], ca);
                    ca = mfma_bf16(ah, w2l[kg], ca);
                } else {
                    cb = mfma_bf16(ah, w2h[kg], cb);
                    cb = mfma_bf16(al, w2h[kg], cb);
                    cb = mfma_bf16(ah, w2l[kg], cb);
                }
            }
        }
        // s32 = 32 keys = half a 64-key chunk
        store_rne2(ca, cb,
                   kv + (size_t)bh * 196608 + (size_t)(s32 >> 1) * 6144
                   + 4096 + (s32 & 1) * 1024, lane);
    }
}

// ---------- fused flash attention (key-split, BARRIER-FREE) ----------
// Grid (64 q, 32 bh, 2 ks); block = 1 wave x 32 q-rows, 1024 keys.
// Staging is WAVE-PRIVATE: producer == consumer, so no __syncthreads at
// all. Double-buffered 2x6KB LDS; fine-grained s_waitcnt vmcnt(6) (wait
// only the previous chunk's 6 global_load_lds; prefetch stays in flight) —
// AITER-style pipeline replacing the R4-R11 vmcnt(0)+barrier drain.
// Partials (o fp32 pi-layout + l) combine exactly in k_out.
__global__ __launch_bounds__(64, 4) void k_attn(
    const char* __restrict__ qb, const char* __restrict__ kvg,
    char* __restrict__ xp, float* __restrict__ lbuf)
{
    __shared__ __align__(16) char kbuf[2][6144];
    const int lane = threadIdx.x & 63;
    const int bh = blockIdx.y, ks = blockIdx.z;
    const int q0 = blockIdx.x * 32;

    const char* qpb = qb + (size_t)bh * 262144 + (size_t)(q0 >> 4) * 2048;
    bfrag qh0 = *(const bfrag*)(qpb + lane * 16);
    bfrag ql0 = *(const bfrag*)(qpb + 1024 + lane * 16);
    bfrag qh1 = *(const bfrag*)(qpb + 2048 + lane * 16);
    bfrag ql1 = *(const bfrag*)(qpb + 3072 + lane * 16);

    const char* kvb = kvg + (size_t)bh * 196608 + (size_t)ks * 98304;

    union { unsigned u[4]; bfrag v; } onesu;
    onesu.u[0] = 0x3F803F80u; onesu.u[1] = 0x3F803F80u;
    onesu.u[2] = 0x3F803F80u; onesu.u[3] = 0x3F803F80u;
    const bfrag ones = onesu.v;

    f4 o0 = {0.f, 0.f, 0.f, 0.f}, o1 = {0.f, 0.f, 0.f, 0.f};
    f4 l0 = {0.f, 0.f, 0.f, 0.f}, l1 = {0.f, 0.f, 0.f, 0.f};

    auto stage = [&](char* db, const char* gsrc) {
#pragma unroll
        for (int i = 0; i < 6; ++i)
            stage16(db + i * 1024, gsrc + i * 1024 + lane * 16);
    };

    stage(kbuf[0], kvb);
    const char* gnext = kvb + 6144;
    int cur = 0;
    for (int ch = 0; ch < 16; ++ch) {
        if (ch < 15) {
            stage(kbuf[cur ^ 1], gnext); gnext += 6144;
            // wait only for chunk ch's 6 loads (prefetch's 6 remain in flight)
            asm volatile("s_waitcnt vmcnt(6)" ::: "memory");
        } else {
            asm volatile("s_waitcnt vmcnt(0)" ::: "memory");
        }
        const char* kb = kbuf[cur];
#pragma unroll
        for (int sub = 0; sub < 2; ++sub) {
            bfrag ka = *(const bfrag*)(kb + (2 * sub) * 1024 + lane * 16);
            bfrag kc2 = *(const bfrag*)(kb + (2 * sub + 1) * 1024 + lane * 16);
            bfrag vf = *(const bfrag*)(kb + 4096 + sub * 1024 + lane * 16);
            {   // q-frag 0
                f4 sa = {0.f, 0.f, 0.f, 0.f}, sb = {0.f, 0.f, 0.f, 0.f};
                sa = mfma_bf16(ka, qh0, sa);  sa = mfma_bf16(ka, ql0, sa);
                sb = mfma_bf16(kc2, qh0, sb); sb = mfma_bf16(kc2, ql0, sb);
                union { unsigned u[4]; bfrag v; } pf;
                pf.u[0] = pk_trunc(fexp2(sa[0]), fexp2(sa[1]));
                pf.u[1] = pk_trunc(fexp2(sa[2]), fexp2(sa[3]));
                pf.u[2] = pk_trunc(fexp2(sb[0]), fexp2(sb[1]));
                pf.u[3] = pk_trunc(fexp2(sb[2]), fexp2(sb[3]));
                o0 = mfma_bf16(vf, pf.v, o0);
                l0 = mfma_bf16(ones, pf.v, l0);
            }
            {   // q-frag 1
                f4 sa = {0.f, 0.f, 0.f, 0.f}, sb = {0.f, 0.f, 0.f, 0.f};
                sa = mfma_bf16(ka, qh1, sa);  sa = mfma_bf16(ka, ql1, sa);
                sb = mfma_bf16(kc2, qh1, sb); sb = mfma_bf16(kc2, ql1, sb);
                union { unsigned u[4]; bfrag v; } pf;
                pf.u[0] = pk_trunc(fexp2(sa[0]), fexp2(sa[1]));
                pf.u[1] = pk_trunc(fexp2(sa[2]), fexp2(sa[3]));
                pf.u[2] = pk_trunc(fexp2(sb[0]), fexp2(sb[1]));
                pf.u[3] = pk_trunc(fexp2(sb[2]), fexp2(sb[3]));
                o1 = mfma_bf16(vf, pf.v, o1);
                l1 = mfma_bf16(ones, pf.v, l1);
            }
        }
        cur ^= 1;
    }

    // epilogue: raw partial sums. o C[m=dim qd*4+r][n=qrow lane&15];
    // xp: [ks][panel][kg=h>>1][half=h&1][lane]16B fp32 f4.
    const int bbk = bh >> 3, h = bh & 7;
    const int gp0 = bbk * 128 + (q0 >> 4);
    char* xw = xp + (size_t)ks * 4194304 + (size_t)gp0 * 8192
             + (h >> 1) * 2048 + (h & 1) * 1024 + lane * 16;
    *(f4*)xw = o0;
    *(f4*)(xw + 8192) = o1;
    if (lane < 16) {   // l rows are n = lane&15 (identical across m-regs)
        float* lw = lbuf + (size_t)ks * 65536 + (size_t)bh * 2048 + q0 + lane;
        lw[0] = l0[0];
        lw[16] = l1[0];
    }
}

// ---------- output projection (combine + MFMA, self-converted Wo) ----------
// Grid (512 panels, 4 tile-pairs) x 64 thr (1 wave).
// Wave: combine key-split partials ((oa+ob)/(la+lb)) -> bf16 A-frag (pi
// layout), self-convert 2 Wo col-tiles (pi layout), 8 MFMA each.
// lbuf indexed [bh][row-in-batch] (R9 bugfix).
__global__ __launch_bounds__(64) void k_out(
    const char* __restrict__ xp, const float* __restrict__ lbuf,
    const float* __restrict__ Wo, const float* __restrict__ bo,
    float* __restrict__ out)
{
    const int lane = threadIdx.x;
    const int n = lane & 15, qd = lane >> 4;
    const int panel = blockIdx.x;
    const int row0 = panel * 16;             // global seq row (for out/xp)
    const int rb = (panel & 127) * 16;       // row within batch (for lbuf)
    const int b = panel >> 7;

    bfrag xf[4];
#pragma unroll
    for (int kg = 0; kg < 4; ++kg) {
        union { unsigned u[4]; bfrag v; } X;
#pragma unroll
        for (int half = 0; half < 2; ++half) {
            const char* pa = xp + (size_t)panel * 8192 + kg * 2048 + half * 1024 + lane * 16;
            f4 oa = *(const f4*)pa;
            f4 ob = *(const f4*)(pa + 4194304);
            int bh = b * 8 + kg * 2 + half;
            float la = lbuf[(size_t)bh * 2048 + rb + n];
            float lb = lbuf[65536 + (size_t)bh * 2048 + rb + n];
            float inv = 1.0f / (la + lb);
            float v0 = (oa[0] + ob[0]) * inv, v1 = (oa[1] + ob[1]) * inv;
            float v2 = (oa[2] + ob[2]) * inv, v3 = (oa[3] + ob[3]) * inv;
            X.u[half * 2] = pk_rne(v0, v1);
            X.u[half * 2 + 1] = pk_rne(v2, v3);
        }
        xf[kg] = X.v;
    }

#pragma unroll
    for (int tt = 0; tt < 2; ++tt) {
        int t = blockIdx.y * 2 + tt;
        float bv = bo[t * 16 + n];
        f4 cacc = {bv, bv, bv, bv};
#pragma unroll
        for (int kg = 0; kg < 4; ++kg) {
            const float* wr = Wo + (size_t)(t * 16 + n) * 128 + kg * 32;
            bfrag wh, wl;
            conv8v(*(const f4*)(wr + qd * 4), *(const f4*)(wr + 16 + qd * 4), wh, wl);
            cacc = mfma_bf16(xf[kg], wh, cacc);
            cacc = mfma_bf16(xf[kg], wl, cacc);
        }
#pragma unroll
        for (int r = 0; r < 4; ++r)
            out[(size_t)(row0 + qd * 4 + r) * 128 + t * 16 + n] = cacc[r];
    }
}

extern "C" void kernel_launch(void* const* d_in, const int* in_sizes, int n_in,
                              void* d_out, int out_size, void* d_ws, size_t ws_size,
                              hipStream_t stream)
{
    const float* query = (const float*)d_in[0];
    const float* key   = (const float*)d_in[1];
    const float* value = (const float*)d_in[2];
    const float* pos   = (const float*)d_in[3];
    const float* W0 = (const float*)d_in[4];
    const float* b0 = (const float*)d_in[5];
    const float* W1 = (const float*)d_in[6];
    const float* b1 = (const float*)d_in[7];
    const float* W2 = (const float*)d_in[8];
    const float* b2 = (const float*)d_in[9];
    const float* Wo = (const float*)d_in[10];
    const float* bo = (const float*)d_in[11];

    char* ws = (char*)d_ws;
    char* qbuf = ws + WS_QB;
    char* kv   = ws + WS_KV;
    char* xp   = ws + WS_XP;
    float* lb  = (float*)(ws + WS_L);
    float* out = (float*)d_out;

    k_proj<<<dim3(256, 2), 256, 0, stream>>>(query, key, value, pos,
                                             W0, W1, W2, b0, b1, b2, qbuf, kv);
    k_attn<<<dim3(64, 32, 2), 64, 0, stream>>>(qbuf, kv, xp, lb);
    k_out<<<dim3(512, 4), 64, 0, stream>>>(xp, lb, Wo, bo, out);
}

// Round 13
// 126.707 us; speedup vs baseline: 1.0307x; 1.0307x over previous
//
#include <hip/hip_runtime.h>
#include <math.h>

#define LOG2E 1.44269504088896340736f

typedef __attribute__((ext_vector_type(8))) short bfrag;   // 8 x bf16
typedef __attribute__((ext_vector_type(4))) float f4;
typedef unsigned __attribute__((ext_vector_type(2))) u2;

// ---------- helpers ----------
// D = (hi16(a)) | (hi16(b)<<16)  -- single v_perm_b32 where available
__device__ __forceinline__ unsigned pk_trunc(float a, float b) {
#if __has_builtin(__builtin_amdgcn_perm)
    return __builtin_amdgcn_perm(__float_as_uint(b), __float_as_uint(a), 0x07060302u);
#else
    return (__float_as_uint(a) >> 16) | (__float_as_uint(b) & 0xFFFF0000u);
#endif
}
__device__ __forceinline__ unsigned pk_rne(float a, float b) {
    unsigned ua = __float_as_uint(a); ua += 0x7FFFu + ((ua >> 16) & 1u);
    unsigned ub = __float_as_uint(b); ub += 0x7FFFu + ((ub >> 16) & 1u);
    return (ua >> 16) | (ub & 0xFFFF0000u);
}
__device__ __forceinline__ float trunchi(float x) {
    return __uint_as_float(__float_as_uint(x) & 0xFFFF0000u);
}
__device__ __forceinline__ float fexp2(float x) {
#if __has_builtin(__builtin_amdgcn_exp2f)
    return __builtin_amdgcn_exp2f(x);
#else
    return exp2f(x);
#endif
}
// async global->LDS, 16B/lane; lds base wave-uniform, HW lands lane i at base+i*16
__device__ __forceinline__ void stage16(void* lds_base, const void* g) {
#if __has_builtin(__builtin_amdgcn_global_load_lds)
    __builtin_amdgcn_global_load_lds(
        (const __attribute__((address_space(1))) unsigned int*)g,
        (__attribute__((address_space(3))) unsigned int*)lds_base, 16, 0, 0);
#else
    int lane = threadIdx.x & 63;
    *(float4*)((char*)lds_base + lane * 16) = *(const float4*)g;
#endif
}
__device__ __forceinline__ f4 mfma_bf16(bfrag a, bfrag b, f4 c) {
    return __builtin_amdgcn_mfma_f32_16x16x32_bf16(a, b, c, 0, 0, 0);
}
// pack two f4 (8 consecutive values) into hi/lo bf16 fragment halves
__device__ __forceinline__ void conv8v(f4 a, f4 b, bfrag& hi, bfrag& lo) {
    union { unsigned u[4]; bfrag v; } H, L;
    H.u[0] = pk_trunc(a.x, a.y); H.u[1] = pk_trunc(a.z, a.w);
    H.u[2] = pk_trunc(b.x, b.y); H.u[3] = pk_trunc(b.z, b.w);
    L.u[0] = pk_trunc(a.x - trunchi(a.x), a.y - trunchi(a.y));
    L.u[1] = pk_trunc(a.z - trunchi(a.z), a.w - trunchi(a.w));
    L.u[2] = pk_trunc(b.x - trunchi(b.x), b.y - trunchi(b.y));
    L.u[3] = pk_trunc(b.z - trunchi(b.z), b.w - trunchi(b.w));
    hi = H.v; lo = L.v;
}
__device__ __forceinline__ void conv8(const float* __restrict__ g, bfrag& hi, bfrag& lo) {
    conv8v(*(const f4*)g, *(const f4*)(g + 4), hi, lo);
}
// scaled variant (scale applied in fp32 BEFORE split)
__device__ __forceinline__ void conv8s(const float* __restrict__ g, float s,
                                       bfrag& hi, bfrag& lo) {
    f4 a = *(const f4*)g, b = *(const f4*)(g + 4);
    a.x *= s; a.y *= s; a.z *= s; a.w *= s;
    b.x *= s; b.y *= s; b.z *= s; b.w *= s;
    conv8v(a, b, hi, lo);
}
// DIRECT packing (no cross-lane): frag k-positions j0..3 = ea regs, j4..7 = eb
// regs. The implied k-permutation is baked consistently into BOTH MFMA
// operands everywhere (q'&k' for S; vt for PV; Wo-pi for out) so it cancels.
__device__ __forceinline__ void store_q2(f4 ea, f4 eb, char* base, int lodelta, int lane) {
    union { unsigned u[4]; bfrag v; } H, L;
    H.u[0] = pk_trunc(ea[0], ea[1]); H.u[1] = pk_trunc(ea[2], ea[3]);
    H.u[2] = pk_trunc(eb[0], eb[1]); H.u[3] = pk_trunc(eb[2], eb[3]);
    L.u[0] = pk_trunc(ea[0] - trunchi(ea[0]), ea[1] - trunchi(ea[1]));
    L.u[1] = pk_trunc(ea[2] - trunchi(ea[2]), ea[3] - trunchi(ea[3]));
    L.u[2] = pk_trunc(eb[0] - trunchi(eb[0]), eb[1] - trunchi(eb[1]));
    L.u[3] = pk_trunc(eb[2] - trunchi(eb[2]), eb[3] - trunchi(eb[3]));
    *(bfrag*)(base + lane * 16) = H.v;
    *(bfrag*)(base + lodelta + lane * 16) = L.v;
}
__device__ __forceinline__ void store_rne2(f4 ea, f4 eb, char* base, int lane) {
    union { unsigned u[4]; bfrag v; } P;
    P.u[0] = pk_rne(ea[0], ea[1]); P.u[1] = pk_rne(ea[2], ea[3]);
    P.u[2] = pk_rne(eb[0], eb[1]); P.u[3] = pk_rne(eb[2], eb[3]);
    *(bfrag*)(base + lane * 16) = P.v;
}

// ---------- workspace byte offsets ----------
// qb:   [bh][128 panels][hi 1KB | lo 1KB]                 = 8,388,608
// kv:   [bh][32 chunks][k 4KB | vt 2KB]  (64 keys/chunk)  = 6,291,456
// xp:   [2 ks][512 panels][4 kg][2 half][64 lanes][16B]   = 8,388,608  (fp32 o partials)
// lbuf: [2 ks][32 bh][2048] fp32                          = 524,288
#define WS_QB 0u
#define WS_KV 8388608u
#define WS_XP 14680064u
#define WS_L  23068672u

// ---------- MFMA projections (input-shared, self-converted W) ----------
// Grid (256, 2): x -> (batch, 32 seq rows), y = head-group (4 heads).
// Block 256 thr: phase 0 stages+converts X once into 64 KB LDS (frag layout);
// phase 1: wave w does head hg*4+w, converting its W slices inline from
// fp32 (L2-hot; identical lane mapping + arithmetic to the old w_prep).
__global__ __launch_bounds__(256) void k_proj(
    const float* __restrict__ query, const float* __restrict__ key,
    const float* __restrict__ value, const float* __restrict__ pos,
    const float* __restrict__ W0, const float* __restrict__ W1,
    const float* __restrict__ W2,
    const float* __restrict__ b0, const float* __restrict__ b1,
    const float* __restrict__ b2,
    char* __restrict__ qb, char* __restrict__ kv)
{
    __shared__ __align__(16) char xlds[65536];   // [arr 4][panel 2][kg 4][hi 1K|lo 1K]
    const int tid = threadIdx.x;
    const int bid = blockIdx.x;
    const int b = bid >> 6, s32 = bid & 63;
    const size_t rowbase = (size_t)(b * 2048 + s32 * 32);

    // ---- phase 0: stage + convert ----
#pragma unroll
    for (int i = 0; i < 8; ++i) {
        int cid = tid + i * 256;                 // 0..2047
        int arr = cid >> 9, rem = cid & 511;
        int c32 = rem >> 4, u = rem & 15;        // row-in-block, dim-chunk
        const float* sp = (arr == 0) ? query : (arr == 1) ? key
                        : (arr == 2) ? value : pos;     // wave-uniform per i
        bfrag hi, lo;
        conv8(sp + (rowbase + c32) * 128 + u * 8, hi, lo);
        int base = arr * 16384 + (c32 >> 4) * 8192 + (u >> 2) * 2048
                 + ((u & 3) * 16 + (c32 & 15)) * 16;
        *(bfrag*)(xlds + base) = hi;
        *(bfrag*)(xlds + base + 1024) = lo;
    }
    __syncthreads();

    // ---- phase 1: one head per wave ----
    const int w = tid >> 6, lane = tid & 63;
    const int n = lane & 15, qd = lane >> 4;
    const int h = blockIdx.y * 4 + w;
    const int bh = b * 8 + h;
    const size_t wrow = (size_t)(h * 16 + n) * 128 + qd * 8;   // W row/cols per lane

    // -- Q: q' = [0.25L*(query W0^T + b0) || L*(pos W0^T + b0)] --
    {
        bfrag wqh[4], wql[4], wph[4], wpl[4];
#pragma unroll
        for (int kg = 0; kg < 4; ++kg) {
            conv8s(W0 + wrow + kg * 32, 0.25f * LOG2E, wqh[kg], wql[kg]);
            conv8s(W0 + wrow + kg * 32, LOG2E, wph[kg], wpl[kg]);
        }
        float bq[4], bp[4];
#pragma unroll
        for (int r = 0; r < 4; ++r) {
            float bv = b0[h * 16 + qd * 4 + r];
            bq[r] = 0.25f * LOG2E * bv; bp[r] = LOG2E * bv;
        }
#pragma unroll
        for (int pp = 0; pp < 2; ++pp) {
            f4 cq = {bq[0], bq[1], bq[2], bq[3]};
            f4 cp = {bp[0], bp[1], bp[2], bp[3]};
#pragma unroll
            for (int kg = 0; kg < 4; ++kg) {
                const char* xq = xlds + 0 * 16384 + pp * 8192 + kg * 2048 + lane * 16;
                const char* xp_ = xlds + 3 * 16384 + pp * 8192 + kg * 2048 + lane * 16;
                bfrag xh = *(const bfrag*)xq, xl = *(const bfrag*)(xq + 1024);
                bfrag ph = *(const bfrag*)xp_, pl = *(const bfrag*)(xp_ + 1024);
                cq = mfma_bf16(wqh[kg], xh, cq);
                cq = mfma_bf16(wqh[kg], xl, cq);
                cq = mfma_bf16(wql[kg], xh, cq);
                cp = mfma_bf16(wph[kg], ph, cp);
                cp = mfma_bf16(wph[kg], pl, cp);
                cp = mfma_bf16(wpl[kg], ph, cp);
            }
            int pg = s32 * 2 + pp;
            store_q2(cq, cp, qb + (size_t)bh * 262144 + (size_t)pg * 2048, 1024, lane);
        }
    }
    // -- K: k' = [(key W1^T + b1) || (pos W1^T + b1)], RNE bf16 --
    {
        bfrag w1h[4], w1l[4];
#pragma unroll
        for (int kg = 0; kg < 4; ++kg)
            conv8(W1 + wrow + kg * 32, w1h[kg], w1l[kg]);
        float bk[4];
#pragma unroll
        for (int r = 0; r < 4; ++r) bk[r] = b1[h * 16 + qd * 4 + r];
#pragma unroll
        for (int pp = 0; pp < 2; ++pp) {
            f4 ck = {bk[0], bk[1], bk[2], bk[3]};
            f4 cpk = {bk[0], bk[1], bk[2], bk[3]};
#pragma unroll
            for (int kg = 0; kg < 4; ++kg) {
                const char* xk = xlds + 1 * 16384 + pp * 8192 + kg * 2048 + lane * 16;
                const char* xp_ = xlds + 3 * 16384 + pp * 8192 + kg * 2048 + lane * 16;
                bfrag xh = *(const bfrag*)xk, xl = *(const bfrag*)(xk + 1024);
                bfrag ph = *(const bfrag*)xp_, pl = *(const bfrag*)(xp_ + 1024);
                ck = mfma_bf16(w1h[kg], xh, ck);
                ck = mfma_bf16(w1h[kg], xl, ck);
                ck = mfma_bf16(w1l[kg], xh, ck);
                cpk = mfma_bf16(w1h[kg], ph, cpk);
                cpk = mfma_bf16(w1h[kg], pl, cpk);
                cpk = mfma_bf16(w1l[kg], ph, cpk);
            }
            int pg = s32 * 2 + pp;   // 16-key panel id; chunk = pg>>2 (64 keys)
            store_rne2(ck, cpk,
                       kv + (size_t)bh * 196608 + (size_t)(pg >> 2) * 6144
                       + (pg & 3) * 1024, lane);
        }
    }
    // -- V: vt = value W2^T + b2 (normal orientation, RNE bf16) --
    {
        bfrag w2h[4], w2l[4];
#pragma unroll
        for (int kg = 0; kg < 4; ++kg)
            conv8(W2 + wrow + kg * 32, w2h[kg], w2l[kg]);
        float bv = b2[h * 16 + n];
        f4 ca = {bv, bv, bv, bv};
        f4 cb = {bv, bv, bv, bv};
#pragma unroll
        for (int pp = 0; pp < 2; ++pp) {
#pragma unroll
            for (int kg = 0; kg < 4; ++kg) {
                const char* xv = xlds + 2 * 16384 + pp * 8192 + kg * 2048 + lane * 16;
                bfrag ah = *(const bfrag*)xv, al = *(const bfrag*)(xv + 1024);
                if (pp == 0) {
                    ca = mfma_bf16(ah, w2h[kg], ca);
                    ca = mfma_bf16(al, w2h[kg], ca);
                    ca = mfma_bf16(ah, w2l[kg], ca);
                } else {
                    cb = mfma_bf16(ah, w2h[kg], cb);
                    cb = mfma_bf16(al, w2h[kg], cb);
                    cb = mfma_bf16(ah, w2l[kg], cb);
                }
            }
        }
        // s32 = 32 keys = half a 64-key chunk
        store_rne2(ca, cb,
                   kv + (size_t)bh * 196608 + (size_t)(s32 >> 1) * 6144
                   + 4096 + (s32 & 1) * 1024, lane);
    }
}

// ---------- fused flash attention (key-split) ----------
// Grid (32 q, 32 bh, 2 ks); block = 2 waves x 32 q-rows; each block does
// 1024 keys (16 chunks of 64). Partials (o fp32 pi-layout + l) combine
// exactly in k_out (no online max -> split-sum is bit-compatible).
// Explicit vmcnt(0) drain before barrier (correctness-critical, R3/R4).
__global__ __launch_bounds__(128, 4) void k_attn(
    const char* __restrict__ qb, const char* __restrict__ kvg,
    char* __restrict__ xp, float* __restrict__ lbuf)
{
    __shared__ __align__(16) char kbuf[2][6144];
    const int tid = threadIdx.x;
    const int w = tid >> 6, lane = tid & 63;
    const int bh = blockIdx.y, ks = blockIdx.z;
    const int q0 = blockIdx.x * 64 + w * 32;

    const char* qpb = qb + (size_t)bh * 262144 + (size_t)(q0 >> 4) * 2048;
    bfrag qh0 = *(const bfrag*)(qpb + lane * 16);
    bfrag ql0 = *(const bfrag*)(qpb + 1024 + lane * 16);
    bfrag qh1 = *(const bfrag*)(qpb + 2048 + lane * 16);
    bfrag ql1 = *(const bfrag*)(qpb + 3072 + lane * 16);

    const char* kvb = kvg + (size_t)bh * 196608 + (size_t)ks * 98304;

    union { unsigned u[4]; bfrag v; } onesu;
    onesu.u[0] = 0x3F803F80u; onesu.u[1] = 0x3F803F80u;
    onesu.u[2] = 0x3F803F80u; onesu.u[3] = 0x3F803F80u;
    const bfrag ones = onesu.v;

    f4 o0 = {0.f, 0.f, 0.f, 0.f}, o1 = {0.f, 0.f, 0.f, 0.f};
    f4 l0 = {0.f, 0.f, 0.f, 0.f}, l1 = {0.f, 0.f, 0.f, 0.f};

    auto stage = [&](char* db, const char* gsrc) {
#pragma unroll
        for (int i = 0; i < 3; ++i)
            stage16(db + (w * 3 + i) * 1024, gsrc + (w * 3 + i) * 1024 + lane * 16);
    };

    stage(kbuf[0], kvb);
    const char* gnext = kvb + 6144;
    int cur = 0;
    for (int ch = 0; ch < 16; ++ch) {
        asm volatile("s_waitcnt vmcnt(0)" ::: "memory");
        __syncthreads();
        if (ch < 15) { stage(kbuf[cur ^ 1], gnext); gnext += 6144; }
        const char* kb = kbuf[cur];
#pragma unroll
        for (int sub = 0; sub < 2; ++sub) {
            bfrag ka = *(const bfrag*)(kb + (2 * sub) * 1024 + lane * 16);
            bfrag kc2 = *(const bfrag*)(kb + (2 * sub + 1) * 1024 + lane * 16);
            bfrag vf = *(const bfrag*)(kb + 4096 + sub * 1024 + lane * 16);
            {   // q-frag 0
                f4 sa = {0.f, 0.f, 0.f, 0.f}, sb = {0.f, 0.f, 0.f, 0.f};
                sa = mfma_bf16(ka, qh0, sa);  sa = mfma_bf16(ka, ql0, sa);
                sb = mfma_bf16(kc2, qh0, sb); sb = mfma_bf16(kc2, ql0, sb);
                union { unsigned u[4]; bfrag v; } pf;
                pf.u[0] = pk_trunc(fexp2(sa[0]), fexp2(sa[1]));
                pf.u[1] = pk_trunc(fexp2(sa[2]), fexp2(sa[3]));
                pf.u[2] = pk_trunc(fexp2(sb[0]), fexp2(sb[1]));
                pf.u[3] = pk_trunc(fexp2(sb[2]), fexp2(sb[3]));
                o0 = mfma_bf16(vf, pf.v, o0);
                l0 = mfma_bf16(ones, pf.v, l0);
            }
            {   // q-frag 1
                f4 sa = {0.f, 0.f, 0.f, 0.f}, sb = {0.f, 0.f, 0.f, 0.f};
                sa = mfma_bf16(ka, qh1, sa);  sa = mfma_bf16(ka, ql1, sa);
                sb = mfma_bf16(kc2, qh1, sb); sb = mfma_bf16(kc2, ql1, sb);
                union { unsigned u[4]; bfrag v; } pf;
                pf.u[0] = pk_trunc(fexp2(sa[0]), fexp2(sa[1]));
                pf.u[1] = pk_trunc(fexp2(sa[2]), fexp2(sa[3]));
                pf.u[2] = pk_trunc(fexp2(sb[0]), fexp2(sb[1]));
                pf.u[3] = pk_trunc(fexp2(sb[2]), fexp2(sb[3]));
                o1 = mfma_bf16(vf, pf.v, o1);
                l1 = mfma_bf16(ones, pf.v, l1);
            }
        }
        cur ^= 1;
    }

    // epilogue: raw partial sums. o C[m=dim qd*4+r][n=qrow lane&15];
    // xp: [ks][panel][kg=h>>1][half=h&1][lane]16B fp32 f4.
    const int bbk = bh >> 3, h = bh & 7;
    const int gp0 = bbk * 128 + (q0 >> 4);
    char* xw = xp + (size_t)ks * 4194304 + (size_t)gp0 * 8192
             + (h >> 1) * 2048 + (h & 1) * 1024 + lane * 16;
    *(f4*)xw = o0;
    *(f4*)(xw + 8192) = o1;
    if (lane < 16) {   // l rows are n = lane&15 (identical across m-regs)
        float* lw = lbuf + (size_t)ks * 65536 + (size_t)bh * 2048 + q0 + lane;
        lw[0] = l0[0];
        lw[16] = l1[0];
    }
}

// ---------- output projection (combine + MFMA, self-converted Wo) ----------
// Grid (512 panels, 4 tile-pairs) x 64 thr (1 wave) = 2048 waves (2/SIMD).
// Wave: combine key-split partials ((oa+ob)/(la+lb)) -> bf16 A-frag (pi
// layout), self-convert 2 Wo col-tiles (pi layout, matching k_attn's x-frag
// order), 8 MFMA each. lbuf indexed [bh][row-in-batch] (R9 bugfix).
__global__ __launch_bounds__(64) void k_out(
    const char* __restrict__ xp, const float* __restrict__ lbuf,
    const float* __restrict__ Wo, const float* __restrict__ bo,
    float* __restrict__ out)
{
    const int lane = threadIdx.x;
    const int n = lane & 15, qd = lane >> 4;
    const int panel = blockIdx.x;
    const int row0 = panel * 16;             // global seq row (for out/xp)
    const int rb = (panel & 127) * 16;       // row within batch (for lbuf)
    const int b = panel >> 7;

    bfrag xf[4];
#pragma unroll
    for (int kg = 0; kg < 4; ++kg) {
        union { unsigned u[4]; bfrag v; } X;
#pragma unroll
        for (int half = 0; half < 2; ++half) {
            const char* pa = xp + (size_t)panel * 8192 + kg * 2048 + half * 1024 + lane * 16;
            f4 oa = *(const f4*)pa;
            f4 ob = *(const f4*)(pa + 4194304);
            int bh = b * 8 + kg * 2 + half;
            float la = lbuf[(size_t)bh * 2048 + rb + n];
            float lb = lbuf[65536 + (size_t)bh * 2048 + rb + n];
            float inv = 1.0f / (la + lb);
            float v0 = (oa[0] + ob[0]) * inv, v1 = (oa[1] + ob[1]) * inv;
            float v2 = (oa[2] + ob[2]) * inv, v3 = (oa[3] + ob[3]) * inv;
            X.u[half * 2] = pk_rne(v0, v1);
            X.u[half * 2 + 1] = pk_rne(v2, v3);
        }
        xf[kg] = X.v;
    }

#pragma unroll
    for (int tt = 0; tt < 2; ++tt) {
        int t = blockIdx.y * 2 + tt;
        float bv = bo[t * 16 + n];
        f4 cacc = {bv, bv, bv, bv};
#pragma unroll
        for (int kg = 0; kg < 4; ++kg) {
            const float* wr = Wo + (size_t)(t * 16 + n) * 128 + kg * 32;
            bfrag wh, wl;
            conv8v(*(const f4*)(wr + qd * 4), *(const f4*)(wr + 16 + qd * 4), wh, wl);
            cacc = mfma_bf16(xf[kg], wh, cacc);
            cacc = mfma_bf16(xf[kg], wl, cacc);
        }
#pragma unroll
        for (int r = 0; r < 4; ++r)
            out[(size_t)(row0 + qd * 4 + r) * 128 + t * 16 + n] = cacc[r];
    }
}

extern "C" void kernel_launch(void* const* d_in, const int* in_sizes, int n_in,
                              void* d_out, int out_size, void* d_ws, size_t ws_size,
                              hipStream_t stream)
{
    const float* query = (const float*)d_in[0];
    const float* key   = (const float*)d_in[1];
    const float* value = (const float*)d_in[2];
    const float* pos   = (const float*)d_in[3];
    const float* W0 = (const float*)d_in[4];
    const float* b0 = (const float*)d_in[5];
    const float* W1 = (const float*)d_in[6];
    const float* b1 = (const float*)d_in[7];
    const float* W2 = (const float*)d_in[8];
    const float* b2 = (const float*)d_in[9];
    const float* Wo = (const float*)d_in[10];
    const float* bo = (const float*)d_in[11];

    char* ws = (char*)d_ws;
    char* qbuf = ws + WS_QB;
    char* kv   = ws + WS_KV;
    char* xp   = ws + WS_XP;
    float* lb  = (float*)(ws + WS_L);
    float* out = (float*)d_out;

    k_proj<<<dim3(256, 2), 256, 0, stream>>>(query, key, value, pos,
                                             W0, W1, W2, b0, b1, b2, qbuf, kv);
    k_attn<<<dim3(32, 32, 2), 128, 0, stream>>>(qbuf, kv, xp, lb);
    k_out<<<dim3(512, 4), 64, 0, stream>>>(xp, lb, Wo, bo, out);
}